// Round 1
// baseline (289.429 us; speedup 1.0000x reference)
//
#include <hip/hip_runtime.h>
#include <hip/hip_bf16.h>

typedef unsigned short u16;
typedef __attribute__((ext_vector_type(8))) short bf16x8;  // 8 bf16 = 4 VGPRs
typedef __attribute__((ext_vector_type(4))) float f32x4;

#define NH   32
#define HD   128
#define SEQ  2048
#define BQ   64
#define BK   64

// Vt swizzle key: phys group p = g ^ vt_key(d) within a d-row of 8 groups
__device__ __forceinline__ int vt_key(int d) { return (d & 7) ^ ((d >> 3) & 7); }

__device__ __forceinline__ u16 f2b(float x) {
  __hip_bfloat16 hb = __float2bfloat16(x);
  return *(u16*)&hb;
}

// load 8 fp32 (32B), convert to bf16x8
__device__ __forceinline__ bf16x8 cvt8(const float* src) {
  float4 a = *(const float4*)(src);
  float4 b = *(const float4*)(src + 4);
  u16 t[8];
  t[0] = f2b(a.x); t[1] = f2b(a.y); t[2] = f2b(a.z); t[3] = f2b(a.w);
  t[4] = f2b(b.x); t[5] = f2b(b.y); t[6] = f2b(b.z); t[7] = f2b(b.w);
  return *(bf16x8*)t;
}

__device__ __forceinline__ bf16x8 cvt8s(const float* src, float sc) {
  float4 a = *(const float4*)(src);
  float4 b = *(const float4*)(src + 4);
  u16 t[8];
  t[0] = f2b(a.x * sc); t[1] = f2b(a.y * sc); t[2] = f2b(a.z * sc); t[3] = f2b(a.w * sc);
  t[4] = f2b(b.x * sc); t[5] = f2b(b.y * sc); t[6] = f2b(b.z * sc); t[7] = f2b(b.w * sc);
  return *(bf16x8*)t;
}

// async global->LDS, 16B per lane; LDS dst must be wave-base + lane*16
__device__ __forceinline__ void dma16(const u16* g, u16* l) {
  __builtin_amdgcn_global_load_lds(
      (const __attribute__((address_space(1))) void*)g,
      (__attribute__((address_space(3))) void*)l, 16, 0, 0);
}

// prep: Kb = bf16(K) same layout [j][h][d]; Vtb = bf16(V) transposed [h][d][j]
__global__ __launch_bounds__(256)
void prep(const float* __restrict__ K, const float* __restrict__ V,
          u16* __restrict__ Kb, u16* __restrict__ Vtb) {
  __shared__ __align__(16) u16 T[64 * 136];
  int b = (int)blockIdx.x;
  int tid = (int)threadIdx.x;
  if (b < 4096) {                       // K: 4096*256*8 = SEQ*NH*HD elems
    size_t i = (size_t)b * 256 + tid;
    bf16x8 v = cvt8(K + i * 8);
    *(uint4*)(Kb + i * 8) = *(uint4*)&v;
  } else {                              // V transpose: 32 heads x 32 j-tiles
    b -= 4096;
    int h = b >> 5, jt = b & 31;
    // stage 64(j) x 128(d) bf16; 16B group g stored at g ^ ((j>>3)&7)
    // (XOR key must use the j-bits that vary across the lanes that would
    //  otherwise alias: row pitch 136 u16 -> 8*pitch ≡ 0 mod 32 banks)
    #pragma unroll
    for (int it = 0; it < 4; ++it) {
      int c = tid + it * 256;           // [0,1024): j = c>>4, grp = c&15
      int j = c >> 4, grp = c & 15;
      bf16x8 v = cvt8(V + ((size_t)(jt * 64 + j) * NH + h) * HD + (grp << 3));
      *(uint4*)(T + j * 136 + ((grp ^ ((j >> 3) & 7)) << 3)) = *(uint4*)&v;
    }
    __syncthreads();
    // each thread emits 2 d-rows x 8 j via 8 paired b32 reads (conflict-free:
    // bank = 4*((d>>3)^k) + (d&7)/2 spans all 32 banks across a wave)
    #pragma unroll
    for (int it = 0; it < 2; ++it) {
      int c = tid + it * 256;           // [0,512): d0 = 2*(c>>3), jg = (c&7)*8
      int d0 = (c >> 3) << 1, k = c & 7, jg = k << 3;
      int off = (((d0 >> 3) ^ k) << 3) | (d0 & 7);
      u16 lo[8], hi[8];
      #pragma unroll
      for (int e = 0; e < 8; ++e) {
        unsigned w = *(const unsigned*)(T + (jg + e) * 136 + off);
        lo[e] = (u16)w; hi[e] = (u16)(w >> 16);
      }
      *(uint4*)(Vtb + ((size_t)h * HD + d0) * SEQ + jt * 64 + jg) = *(uint4*)lo;
      *(uint4*)(Vtb + ((size_t)h * HD + d0 + 1) * SEQ + jt * 64 + jg) = *(uint4*)hi;
    }
  }
}

template <bool PRE>
__global__ __launch_bounds__(256, 4)
void attn_roco(const float* __restrict__ Qg, const float* __restrict__ Kg,
               const float* __restrict__ Vg, const u16* __restrict__ Kb,
               const u16* __restrict__ Vtb, float* __restrict__ Og,
               float* __restrict__ ws) {
  // union: pass A (PRE) KsA 128x128 = 32KB  |  pass B Ks 16KB + Vt 16KB; + Ps 8KB
  // 40960 B x 4 blocks = 163840 B = exactly 160 KiB/CU -> 4 blocks/CU
  __shared__ __align__(16) u16 smem[20480];
  u16* KsA = smem;            // pass A PRE: [row][phys-grp], linear, XOR in src
  u16* Ks  = smem;            // pass B: 64x128, phys grp = g ^ (row&15)
  u16* Vt  = smem + 8192;     // pass B: [d][64j], phys grp = g ^ vt_key(d)
  u16* Ps  = smem + 16384;    // 64x64, phys grp = pg ^ (prow&7)

  const int tid = threadIdx.x;
  const int wv  = tid >> 6;
  const int ln  = tid & 63;
  const int qd  = ln >> 4;
  const int cc  = ln & 15;

  const int h = (int)blockIdx.x & 31;
  // serpentine schedule: per-CU tile-work sums to a constant under RR dispatch
  const int pos = ((int)blockIdx.x >> 5) & 7;
  const int grp = (int)blockIdx.x >> 8;
  int qt;
  if      (grp == 0) qt = 31 - pos;
  else if (grp == 1) qt = 16 + pos;
  else if (grp == 2) qt = 15 - pos;
  else               qt = pos;

  const int qbase  = qt * BQ;
  const int ntiles = qt + 1;

  // ---- Q tile into registers, pre-scaled by beta*log2e ----
  const float qsc = 0.08838834764831845f * 1.4426950408889634f;
  bf16x8 qf[4];
  {
    const float* qp = Qg + ((size_t)(qbase + wv * 16 + cc) * NH + h) * HD;
    #pragma unroll
    for (int kd = 0; kd < 4; ++kd)
      qf[kd] = cvt8s(qp + kd * 32 + qd * 8, qsc);
  }

  const int rbase = wv * 16 + qd * 4;
  float ls[4] = {0.f, 0.f, 0.f, 0.f};

  // ================= PASS A: row sumexp (no max — scores bounded) =========
  if (PRE) {
    const int ntA = (qt >> 1) + 1;           // BK=128 tiles
    for (int ta = 0; ta < ntA; ++ta) {
      __syncthreads();                       // WAR on KsA
      #pragma unroll
      for (int it = 0; it < 8; ++it) {
        int c = it * 256 + tid;              // [0,2048): row = c>>4, p = c&15
        int row = c >> 4, g = (c & 15) ^ (row & 15);
        dma16(Kb + ((size_t)(ta * 128 + row) * NH + h) * HD + (g << 3),
              KsA + (size_t)c * 8);
      }
      __syncthreads();                       // DMA drained + visible

      f32x4 S[8];
      #pragma unroll
      for (int f = 0; f < 8; ++f)
        #pragma unroll
        for (int r = 0; r < 4; ++r) S[f][r] = 0.f;

      #pragma unroll
      for (int kd = 0; kd < 4; ++kd) {
        #pragma unroll
        for (int f = 0; f < 8; ++f) {
          bf16x8 b = *(const bf16x8*)(KsA + (f * 16 + cc) * 128 +
                                      (((kd * 4 + qd) ^ cc) << 3));
          S[f] = __builtin_amdgcn_mfma_f32_16x16x32_bf16(qf[kd], b, S[f], 0, 0, 0);
        }
      }

      const bool last = (ta == ntA - 1);
      #pragma unroll
      for (int r = 0; r < 4; ++r) {
        const int ig = qbase + rbase + r;
        float acc = 0.f;
        #pragma unroll
        for (int f = 0; f < 8; ++f) {
          float e = __builtin_amdgcn_exp2f(S[f][r]);
          if (last && (ta * 128 + f * 16 + cc) > ig) e = 0.f;
          acc += e;
        }
        ls[r] += acc;
      }
    }
  } else {
    for (int t = 0; t < ntiles; ++t) {
      __syncthreads();
      #pragma unroll
      for (int it = 0; it < 4; ++it) {
        int c = tid + it * 256;
        int row = c >> 4, g = c & 15;
        bf16x8 kv = cvt8(Kg + ((size_t)(t * BK + row) * NH + h) * HD + (g << 3));
        *(uint4*)(Ks + row * 128 + ((g ^ (row & 15)) << 3)) = *(uint4*)&kv;
      }
      __syncthreads();

      f32x4 S[4];
      #pragma unroll
      for (int f = 0; f < 4; ++f)
        #pragma unroll
        for (int r = 0; r < 4; ++r) S[f][r] = 0.f;

      #pragma unroll
      for (int kd = 0; kd < 4; ++kd) {
        #pragma unroll
        for (int f = 0; f < 4; ++f) {
          bf16x8 b = *(const bf16x8*)(Ks + (f * 16 + cc) * 128 +
                                      (((kd * 4 + qd) ^ cc) << 3));
          S[f] = __builtin_amdgcn_mfma_f32_16x16x32_bf16(qf[kd], b, S[f], 0, 0, 0);
        }
      }

      const bool diag = (t == qt);
      #pragma unroll
      for (int r = 0; r < 4; ++r) {
        const int iloc = rbase + r;
        float acc = 0.f;
        #pragma unroll
        for (int f = 0; f < 4; ++f) {
          float e = __builtin_amdgcn_exp2f(S[f][r]);
          if (diag && (f * 16 + cc) > iloc) e = 0.f;
          acc += e;
        }
        ls[r] += acc;
      }
    }
  }

  // ---- one-shot row reduce ----
  float invl[4];
  #pragma unroll
  for (int r = 0; r < 4; ++r) {
    #pragma unroll
    for (int off = 1; off < 16; off <<= 1)
      ls[r] += __shfl_xor(ls[r], off);
    invl[r] = 1.f / ls[r];
  }

  f32x4 O[8];
  #pragma unroll
  for (int f = 0; f < 8; ++f)
    #pragma unroll
    for (int r = 0; r < 4; ++r) O[f][r] = 0.f;

  float* ws_s = ws + (size_t)h * SEQ;
  float* ws_q = ws + (size_t)NH * SEQ + (size_t)h * SEQ;

  // ================= PASS B: exact P, O += P*V, column sums =================
  for (int t = 0; t < ntiles; ++t) {
    __syncthreads();                         // WAR
    if (PRE) {
      #pragma unroll
      for (int it = 0; it < 4; ++it) {
        int c = it * 256 + tid;              // [0,1024): K tile 64x128
        int row = c >> 4, g = (c & 15) ^ (row & 15);
        dma16(Kb + ((size_t)(t * BK + row) * NH + h) * HD + (g << 3),
              Ks + (size_t)c * 8);
      }
      #pragma unroll
      for (int it = 0; it < 4; ++it) {
        int c = it * 256 + tid;              // [0,1024): V tile [d][64j]
        int d = c >> 3, g = (c & 7) ^ vt_key(d);
        dma16(Vtb + ((size_t)h * HD + d) * SEQ + t * BK + (g << 3),
              Vt + (size_t)c * 8);
      }
    } else {
      #pragma unroll
      for (int it = 0; it < 4; ++it) {
        int c = tid + it * 256;
        int row = c >> 4, g = c & 15;
        bf16x8 kv = cvt8(Kg + ((size_t)(t * BK + row) * NH + h) * HD + (g << 3));
        *(uint4*)(Ks + row * 128 + ((g ^ (row & 15)) << 3)) = *(uint4*)&kv;
      }
      #pragma unroll
      for (int it = 0; it < 4; ++it) {
        int c = tid + it * 256;
        int j = c >> 4, d0 = (c & 15) << 3;
        bf16x8 v = cvt8(Vg + ((size_t)(t * BK + j) * NH + h) * HD + d0);
        u16 ev[8];
        *(uint4*)ev = *(uint4*)&v;
        #pragma unroll
        for (int e = 0; e < 8; ++e) {
          int d = d0 + e;
          Vt[d * BK + ((((j >> 3) ^ vt_key(d)) << 3)) + (j & 7)] = ev[e];
        }
      }
    }
    __syncthreads();                         // staging visible

    f32x4 S[4];
    #pragma unroll
    for (int f = 0; f < 4; ++f)
      #pragma unroll
      for (int r = 0; r < 4; ++r) S[f][r] = 0.f;

    #pragma unroll
    for (int kd = 0; kd < 4; ++kd) {
      #pragma unroll
      for (int f = 0; f < 4; ++f) {
        bf16x8 b = *(const bf16x8*)(Ks + (f * 16 + cc) * 128 +
                                    (((kd * 4 + qd) ^ cc) << 3));
        S[f] = __builtin_amdgcn_mfma_f32_16x16x32_bf16(qf[kd], b, S[f], 0, 0, 0);
      }
    }

    const bool diag = (t == qt);
    float cs[4] = {0.f, 0.f, 0.f, 0.f}, cq[4] = {0.f, 0.f, 0.f, 0.f};
    #pragma unroll
    for (int r = 0; r < 4; ++r) {
      const int iloc = rbase + r;
      const int prow = wv * 16 + qd * 4 + r;
      #pragma unroll
      for (int f = 0; f < 4; ++f) {
        float p = __builtin_amdgcn_exp2f(S[f][r]) * invl[r];
        if (diag && (f * 16 + cc) > iloc) p = 0.f;
        cs[f] += p;
        cq[f] += p * p;
        int pg = f * 2 + (cc >> 3);
        Ps[prow * 64 + ((pg ^ (prow & 7)) << 3) + (cc & 7)] = f2b(p);
      }
    }
    // column sums: combine quads, one atomic per column per wave
    #pragma unroll
    for (int f = 0; f < 4; ++f) {
      cs[f] += __shfl_xor(cs[f], 16); cs[f] += __shfl_xor(cs[f], 32);
      cq[f] += __shfl_xor(cq[f], 16); cq[f] += __shfl_xor(cq[f], 32);
      if (qd == f) {
        int j = t * BK + f * 16 + cc;
        atomicAdd(ws_s + j, cs[f]);
        atomicAdd(ws_q + j, cq[f]);
      }
    }
    // PV: O[16 x 128] += P[16 x 64] * V[64 x 128]
    #pragma unroll
    for (int ks = 0; ks < 2; ++ks) {
      bf16x8 a = *(const bf16x8*)(Ps + (wv * 16 + cc) * 64 +
                                  (((ks * 4 + qd) ^ (cc & 7)) << 3));
      #pragma unroll
      for (int f2 = 0; f2 < 8; ++f2) {
        int d = f2 * 16 + cc;
        int jb = ks * 4 + qd;
        bf16x8 b = *(const bf16x8*)(Vt + d * BK + ((jb ^ vt_key(d)) << 3));
        O[f2] = __builtin_amdgcn_mfma_f32_16x16x32_bf16(a, b, O[f2], 0, 0, 0);
      }
    }
  }

  // ---- epilogue: O already normalized (invl folded into P) ----
  #pragma unroll
  for (int f2 = 0; f2 < 8; ++f2) {
    #pragma unroll
    for (int r = 0; r < 4; ++r) {
      int i = qbase + rbase + r;
      int d = f2 * 16 + cc;
      Og[((size_t)i * NH + h) * HD + d] = O[f2][r];
    }
  }
}

__global__ void roco_fin(const float* __restrict__ ws, float* __restrict__ out) {
  int i = (int)blockIdx.x * 256 + (int)threadIdx.x;
  out[i] = ws[i];
}

extern "C" void kernel_launch(void* const* d_in, const int* in_sizes, int n_in,
                              void* d_out, int out_size, void* d_ws, size_t ws_size,
                              hipStream_t stream) {
  (void)in_sizes; (void)n_in; (void)out_size;
  const float* Qg = (const float*)d_in[0];
  const float* Kg = (const float*)d_in[1];
  const float* Vg = (const float*)d_in[2];
  float* Og = (float*)d_out;
  float* ws = (float*)d_ws;

  const size_t roco_elems = (size_t)2 * NH * SEQ;
  const size_t tens = (size_t)SEQ * NH * HD;
  const size_t need = roco_elems * 4 + 2 * tens * 2;
  const bool pre = ws_size >= need;

  (void)hipMemsetAsync(d_ws, 0, roco_elems * sizeof(float), stream);

  u16* Kb  = (u16*)(ws + roco_elems);
  u16* Vtb = Kb + tens;

  if (pre) {
    prep<<<dim3(4096 + 1024), dim3(256), 0, stream>>>(Kg, Vg, Kb, Vtb);
    attn_roco<true><<<dim3(NH * (SEQ / BQ)), dim3(256), 0, stream>>>(
        Qg, Kg, Vg, Kb, Vtb, Og, ws);
  } else {
    attn_roco<false><<<dim3(NH * (SEQ / BQ)), dim3(256), 0, stream>>>(
        Qg, Kg, Vg, Kb, Vtb, Og, ws);
  }

  roco_fin<<<dim3((2 * NH * SEQ) / 256), dim3(256), 0, stream>>>(
      ws, Og + tens);
}

// Round 2
// 230.334 us; speedup vs baseline: 1.2566x; 1.2566x over previous
//
#include <hip/hip_runtime.h>
#include <hip/hip_bf16.h>

typedef unsigned short u16;
typedef __attribute__((ext_vector_type(8))) short bf16x8;  // 8 bf16 = 4 VGPRs
typedef __attribute__((ext_vector_type(4))) float f32x4;

#define NH   32
#define HD   128
#define SEQ  2048
#define BQ   64
#define BK   64

// smem layout (u16 units): Ks dbuf [0,16384), Vt dbuf [16384,32768), Ps [32768,36864)
// pass A overlays: KsA buf0 = [0,16384), KsA buf1 = [16384,32768)
#define VT_OFF 16384
#define PS_OFF 32768

// Vt swizzle key: phys group p = g ^ vt_key(d) within a d-row of 8 groups
__device__ __forceinline__ int vt_key(int d) { return (d & 7) ^ ((d >> 3) & 7); }

__device__ __forceinline__ u16 f2b(float x) {
  __hip_bfloat16 hb = __float2bfloat16(x);
  return *(u16*)&hb;
}

// load 8 fp32 (32B), convert to bf16x8
__device__ __forceinline__ bf16x8 cvt8(const float* src) {
  float4 a = *(const float4*)(src);
  float4 b = *(const float4*)(src + 4);
  u16 t[8];
  t[0] = f2b(a.x); t[1] = f2b(a.y); t[2] = f2b(a.z); t[3] = f2b(a.w);
  t[4] = f2b(b.x); t[5] = f2b(b.y); t[6] = f2b(b.z); t[7] = f2b(b.w);
  return *(bf16x8*)t;
}

__device__ __forceinline__ bf16x8 cvt8s(const float* src, float sc) {
  float4 a = *(const float4*)(src);
  float4 b = *(const float4*)(src + 4);
  u16 t[8];
  t[0] = f2b(a.x * sc); t[1] = f2b(a.y * sc); t[2] = f2b(a.z * sc); t[3] = f2b(a.w * sc);
  t[4] = f2b(b.x * sc); t[5] = f2b(b.y * sc); t[6] = f2b(b.z * sc); t[7] = f2b(b.w * sc);
  return *(bf16x8*)t;
}

// async global->LDS, 16B per lane; LDS dst must be wave-base + lane*16
__device__ __forceinline__ void dma16(const u16* g, u16* l) {
  __builtin_amdgcn_global_load_lds(
      (const __attribute__((address_space(1))) void*)g,
      (__attribute__((address_space(3))) void*)l, 16, 0, 0);
}

// prep: Kb = bf16(K) same layout [j][h][d]; Vtb = bf16(V) transposed [h][d][j]
__global__ __launch_bounds__(256)
void prep(const float* __restrict__ K, const float* __restrict__ V,
          u16* __restrict__ Kb, u16* __restrict__ Vtb) {
  __shared__ __align__(16) u16 T[64 * 136];
  int b = (int)blockIdx.x;
  int tid = (int)threadIdx.x;
  if (b < 4096) {                       // K: 4096*256*8 = SEQ*NH*HD elems
    size_t i = (size_t)b * 256 + tid;
    bf16x8 v = cvt8(K + i * 8);
    *(uint4*)(Kb + i * 8) = *(uint4*)&v;
  } else {                              // V transpose: 32 heads x 32 j-tiles
    b -= 4096;
    int h = b >> 5, jt = b & 31;
    // stage 64(j) x 128(d) bf16; 16B group g stored at g ^ ((j>>3)&7)
    #pragma unroll
    for (int it = 0; it < 4; ++it) {
      int c = tid + it * 256;           // [0,1024): j = c>>4, grp = c&15
      int j = c >> 4, grp = c & 15;
      bf16x8 v = cvt8(V + ((size_t)(jt * 64 + j) * NH + h) * HD + (grp << 3));
      *(uint4*)(T + j * 136 + ((grp ^ ((j >> 3) & 7)) << 3)) = *(uint4*)&v;
    }
    __syncthreads();
    // each thread emits 2 d-rows x 8 j via 8 paired b32 reads (conflict-free)
    #pragma unroll
    for (int it = 0; it < 2; ++it) {
      int c = tid + it * 256;           // [0,512): d0 = 2*(c>>3), jg = (c&7)*8
      int d0 = (c >> 3) << 1, k = c & 7, jg = k << 3;
      int off = (((d0 >> 3) ^ k) << 3) | (d0 & 7);
      u16 lo[8], hi[8];
      #pragma unroll
      for (int e = 0; e < 8; ++e) {
        unsigned w = *(const unsigned*)(T + (jg + e) * 136 + off);
        lo[e] = (u16)w; hi[e] = (u16)(w >> 16);
      }
      *(uint4*)(Vtb + ((size_t)h * HD + d0) * SEQ + jt * 64 + jg) = *(uint4*)lo;
      *(uint4*)(Vtb + ((size_t)h * HD + d0 + 1) * SEQ + jt * 64 + jg) = *(uint4*)hi;
    }
  }
}

template <bool PRE>
__global__ __launch_bounds__(256, 2)
void attn_roco(const float* __restrict__ Qg, const float* __restrict__ Kg,
               const float* __restrict__ Vg, const u16* __restrict__ Kb,
               const u16* __restrict__ Vtb, float* __restrict__ Og,
               float* __restrict__ RS) {
  // 72 KiB: double-buffered Ks + Vt (1 barrier/tile pipeline) + Ps
  __shared__ __align__(16) u16 smem[36864];
  u16* Ks = smem;             // dbuf 2x 64x128, phys grp = g ^ (row&15)
  u16* Vt = smem + VT_OFF;    // dbuf 2x [d][64j], phys grp = g ^ vt_key(d)
  u16* Ps = smem + PS_OFF;    // 64x64, phys grp = pg ^ (prow&7)

  const int tid = threadIdx.x;
  const int wv  = tid >> 6;
  const int ln  = tid & 63;
  const int qd  = ln >> 4;
  const int cc  = ln & 15;

  const int h = (int)blockIdx.x & 31;
  // serpentine schedule: per-CU tile-work sums to a constant under RR dispatch
  const int pos = ((int)blockIdx.x >> 5) & 7;
  const int grp = (int)blockIdx.x >> 8;
  int qt;
  if      (grp == 0) qt = 31 - pos;
  else if (grp == 1) qt = 16 + pos;
  else if (grp == 2) qt = 15 - pos;
  else               qt = pos;

  const int qbase  = qt * BQ;
  const int ntiles = qt + 1;

  // ---- Q tile into registers, pre-scaled by beta*log2e ----
  const float qsc = 0.08838834764831845f * 1.4426950408889634f;
  bf16x8 qf[4];
  {
    const float* qp = Qg + ((size_t)(qbase + wv * 16 + cc) * NH + h) * HD;
    #pragma unroll
    for (int kd = 0; kd < 4; ++kd)
      qf[kd] = cvt8s(qp + kd * 32 + qd * 8, qsc);
  }

  const int rbase = wv * 16 + qd * 4;
  float ls[4] = {0.f, 0.f, 0.f, 0.f};

  // stage lambdas (PRE path): tile -> LDS buffer via async DMA
  auto stageA = [&](int ta, int cur) {
    u16* ka = smem + cur * 16384;
    #pragma unroll
    for (int it = 0; it < 8; ++it) {
      int c = it * 256 + tid;            // [0,2048): row = c>>4
      int row = c >> 4, g = (c & 15) ^ (row & 15);
      dma16(Kb + ((size_t)(ta * 128 + row) * NH + h) * HD + (g << 3),
            ka + (size_t)c * 8);
    }
  };
  auto stageB = [&](int t, int cur) {
    u16* ks = Ks + cur * 8192;
    u16* vt = Vt + cur * 8192;
    #pragma unroll
    for (int it = 0; it < 4; ++it) {
      int c = it * 256 + tid;            // K tile 64x128
      int row = c >> 4, g = (c & 15) ^ (row & 15);
      dma16(Kb + ((size_t)(t * BK + row) * NH + h) * HD + (g << 3),
            ks + (size_t)c * 8);
    }
    #pragma unroll
    for (int it = 0; it < 4; ++it) {
      int c = it * 256 + tid;            // V tile [d][64j]
      int d = c >> 3, g = (c & 7) ^ vt_key(d);
      dma16(Vtb + ((size_t)h * HD + d) * SEQ + t * BK + (g << 3),
            vt + (size_t)c * 8);
    }
  };

  // ================= PASS A: row sumexp (no max — scores bounded) =========
  if (PRE) {
    const int ntA = (qt >> 1) + 1;           // BK=128 tiles, dbuf 2x32KB
    stageA(0, 0);
    for (int ta = 0; ta < ntA; ++ta) {
      const int cur = ta & 1;
      __syncthreads();                       // drains this tile's DMA + sync
      if (ta + 1 < ntA) stageA(ta + 1, cur ^ 1);   // prefetch next tile

      const u16* ka = smem + cur * 16384;
      f32x4 S[8];
      #pragma unroll
      for (int f = 0; f < 8; ++f)
        #pragma unroll
        for (int r = 0; r < 4; ++r) S[f][r] = 0.f;

      #pragma unroll
      for (int kd = 0; kd < 4; ++kd) {
        #pragma unroll
        for (int f = 0; f < 8; ++f) {
          bf16x8 b = *(const bf16x8*)(ka + (f * 16 + cc) * 128 +
                                      (((kd * 4 + qd) ^ cc) << 3));
          S[f] = __builtin_amdgcn_mfma_f32_16x16x32_bf16(qf[kd], b, S[f], 0, 0, 0);
        }
      }

      const bool last = (ta == ntA - 1);
      #pragma unroll
      for (int r = 0; r < 4; ++r) {
        const int ig = qbase + rbase + r;
        float acc = 0.f;
        #pragma unroll
        for (int f = 0; f < 8; ++f) {
          float e = __builtin_amdgcn_exp2f(S[f][r]);
          if (last && (ta * 128 + f * 16 + cc) > ig) e = 0.f;
          acc += e;
        }
        ls[r] += acc;
      }
    }
    __syncthreads();   // all waves done reading KsA before pass-B staging
  } else {
    for (int t = 0; t < ntiles; ++t) {
      __syncthreads();
      #pragma unroll
      for (int it = 0; it < 4; ++it) {
        int c = tid + it * 256;
        int row = c >> 4, g = c & 15;
        bf16x8 kv = cvt8(Kg + ((size_t)(t * BK + row) * NH + h) * HD + (g << 3));
        *(uint4*)(Ks + row * 128 + ((g ^ (row & 15)) << 3)) = *(uint4*)&kv;
      }
      __syncthreads();

      f32x4 S[4];
      #pragma unroll
      for (int f = 0; f < 4; ++f)
        #pragma unroll
        for (int r = 0; r < 4; ++r) S[f][r] = 0.f;

      #pragma unroll
      for (int kd = 0; kd < 4; ++kd) {
        #pragma unroll
        for (int f = 0; f < 4; ++f) {
          bf16x8 b = *(const bf16x8*)(Ks + (f * 16 + cc) * 128 +
                                      (((kd * 4 + qd) ^ cc) << 3));
          S[f] = __builtin_amdgcn_mfma_f32_16x16x32_bf16(qf[kd], b, S[f], 0, 0, 0);
        }
      }

      const bool diag = (t == qt);
      #pragma unroll
      for (int r = 0; r < 4; ++r) {
        const int iloc = rbase + r;
        float acc = 0.f;
        #pragma unroll
        for (int f = 0; f < 4; ++f) {
          float e = __builtin_amdgcn_exp2f(S[f][r]);
          if (diag && (f * 16 + cc) > iloc) e = 0.f;
          acc += e;
        }
        ls[r] += acc;
      }
    }
  }

  // ---- one-shot row reduce ----
  float invl[4];
  #pragma unroll
  for (int r = 0; r < 4; ++r) {
    #pragma unroll
    for (int off = 1; off < 16; off <<= 1)
      ls[r] += __shfl_xor(ls[r], off);
    invl[r] = 1.f / ls[r];
  }

  f32x4 O[8];
  #pragma unroll
  for (int f = 0; f < 8; ++f)
    #pragma unroll
    for (int r = 0; r < 4; ++r) O[f][r] = 0.f;

  float* ws_s = RS + (size_t)h * SEQ;
  float* ws_q = RS + (size_t)NH * SEQ + (size_t)h * SEQ;

  // ================= PASS B: exact P, O += P*V, column sums =================
  if (PRE) stageB(0, 0);
  for (int t = 0; t < ntiles; ++t) {
    const int cur = PRE ? (t & 1) : 0;
    __syncthreads();                         // drains tile-t DMA + sync
    if (PRE) {
      if (t + 1 < ntiles) stageB(t + 1, cur ^ 1);   // prefetch next tile
    } else {
      #pragma unroll
      for (int it = 0; it < 4; ++it) {
        int c = tid + it * 256;
        int row = c >> 4, g = c & 15;
        bf16x8 kv = cvt8(Kg + ((size_t)(t * BK + row) * NH + h) * HD + (g << 3));
        *(uint4*)(Ks + row * 128 + ((g ^ (row & 15)) << 3)) = *(uint4*)&kv;
      }
      #pragma unroll
      for (int it = 0; it < 4; ++it) {
        int c = tid + it * 256;
        int j = c >> 4, d0 = (c & 15) << 3;
        bf16x8 v = cvt8(Vg + ((size_t)(t * BK + j) * NH + h) * HD + d0);
        u16 ev[8];
        *(uint4*)ev = *(uint4*)&v;
        #pragma unroll
        for (int e = 0; e < 8; ++e) {
          int d = d0 + e;
          Vt[d * BK + ((((j >> 3) ^ vt_key(d)) << 3)) + (j & 7)] = ev[e];
        }
      }
      __syncthreads();                       // non-PRE: staging visible
    }

    const u16* ks = Ks + cur * 8192;
    const u16* vt = Vt + cur * 8192;

    f32x4 S[4];
    #pragma unroll
    for (int f = 0; f < 4; ++f)
      #pragma unroll
      for (int r = 0; r < 4; ++r) S[f][r] = 0.f;

    #pragma unroll
    for (int kd = 0; kd < 4; ++kd) {
      #pragma unroll
      for (int f = 0; f < 4; ++f) {
        bf16x8 b = *(const bf16x8*)(ks + (f * 16 + cc) * 128 +
                                    (((kd * 4 + qd) ^ cc) << 3));
        S[f] = __builtin_amdgcn_mfma_f32_16x16x32_bf16(qf[kd], b, S[f], 0, 0, 0);
      }
    }

    const bool diag = (t == qt);
    float cs[4] = {0.f, 0.f, 0.f, 0.f}, cq[4] = {0.f, 0.f, 0.f, 0.f};
    #pragma unroll
    for (int r = 0; r < 4; ++r) {
      const int iloc = rbase + r;
      const int prow = wv * 16 + qd * 4 + r;
      #pragma unroll
      for (int f = 0; f < 4; ++f) {
        float p = __builtin_amdgcn_exp2f(S[f][r]) * invl[r];
        if (diag && (f * 16 + cc) > iloc) p = 0.f;
        cs[f] += p;
        cq[f] += p * p;
        int pg = f * 2 + (cc >> 3);
        Ps[prow * 64 + ((pg ^ (prow & 7)) << 3) + (cc & 7)] = f2b(p);
      }
    }
    // column sums: combine quads, one atomic per column per wave
    #pragma unroll
    for (int f = 0; f < 4; ++f) {
      cs[f] += __shfl_xor(cs[f], 16); cs[f] += __shfl_xor(cs[f], 32);
      cq[f] += __shfl_xor(cq[f], 16); cq[f] += __shfl_xor(cq[f], 32);
      if (qd == f) {
        int j = t * BK + f * 16 + cc;
        atomicAdd(ws_s + j, cs[f]);
        atomicAdd(ws_q + j, cq[f]);
      }
    }
    // PV: O[16 x 128] += P[16 x 64] * V[64 x 128]
    #pragma unroll
    for (int ks2 = 0; ks2 < 2; ++ks2) {
      bf16x8 a = *(const bf16x8*)(Ps + (wv * 16 + cc) * 64 +
                                  (((ks2 * 4 + qd) ^ (cc & 7)) << 3));
      #pragma unroll
      for (int f2 = 0; f2 < 8; ++f2) {
        int d = f2 * 16 + cc;
        int jb = ks2 * 4 + qd;
        bf16x8 b = *(const bf16x8*)(vt + d * BK + ((jb ^ vt_key(d)) << 3));
        O[f2] = __builtin_amdgcn_mfma_f32_16x16x32_bf16(a, b, O[f2], 0, 0, 0);
      }
    }
  }

  // ---- epilogue: O already normalized (invl folded into P) ----
  #pragma unroll
  for (int f2 = 0; f2 < 8; ++f2) {
    #pragma unroll
    for (int r = 0; r < 4; ++r) {
      int i = qbase + rbase + r;
      int d = f2 * 16 + cc;
      Og[((size_t)i * NH + h) * HD + d] = O[f2][r];
    }
  }
}

extern "C" void kernel_launch(void* const* d_in, const int* in_sizes, int n_in,
                              void* d_out, int out_size, void* d_ws, size_t ws_size,
                              hipStream_t stream) {
  (void)in_sizes; (void)n_in; (void)out_size;
  const float* Qg = (const float*)d_in[0];
  const float* Kg = (const float*)d_in[1];
  const float* Vg = (const float*)d_in[2];
  float* Og = (float*)d_out;

  const size_t roco_elems = (size_t)2 * NH * SEQ;
  const size_t tens = (size_t)SEQ * NH * HD;
  const size_t need = 2 * tens * 2;         // Kb + Vtb (bf16)
  const bool pre = ws_size >= need;

  // roco accumulators live directly in the output buffer (drops roco_fin)
  float* RS = Og + tens;
  (void)hipMemsetAsync(RS, 0, roco_elems * sizeof(float), stream);

  u16* Kb  = (u16*)d_ws;
  u16* Vtb = Kb + tens;

  if (pre) {
    prep<<<dim3(4096 + 1024), dim3(256), 0, stream>>>(Kg, Vg, Kb, Vtb);
    attn_roco<true><<<dim3(NH * (SEQ / BQ)), dim3(256), 0, stream>>>(
        Qg, Kg, Vg, Kb, Vtb, Og, RS);
  } else {
    attn_roco<false><<<dim3(NH * (SEQ / BQ)), dim3(256), 0, stream>>>(
        Qg, Kg, Vg, Kb, Vtb, Og, RS);
  }
}